// Round 12
// baseline (188.111 us; speedup 1.0000x reference)
//
#include <hip/hip_runtime.h>

// GLA forward, chunked. T=2048, B=8, IN=512, DV=512, NK=128, CHUNK=128, NCH=16.
// Round 16: proj_mfma K-loop = A-double-buffer with ONE plain __syncthreads
// per iter (stage(nxt) issued right after the barrier, flies under compute;
// the NEXT iter's __syncthreads drains it — vmcnt(0)+s_barrier semantics make
// this race-free, unlike R8's counted-vmcnt version). B is NOT staged: W
// fragments read direct from global (16KB/iter working set = L1-resident;
// W per XCD L2-resident under the bid%8==mt%8 remap; pattern proven in R13
// ymm P1). LDS stays 34816B -> 4 blocks/CU. Everything else = R15/R13.
//
// Layouts (cb = c*8+b, r = t_glob*8+b):
//   a_buf  fp32 [r][128]
//   k_raw/q_raw bf16 [r][128]
//   qb/kbs bf16 [r][128]          (q~ = q*cp, k~ = k/(cp+eps))
//   kt     bf16 [cb*128 + n][s]   (k~ transposed)
//   vt     bf16 [cb*512 + d][s]
//   Gt     bf16 [cb*512 + d][n]   (scan input, overlays xb)
//   St     bf16 [cb*512 + d][n]   (S_prev per chunk)

#define EPSV 1e-8f

typedef __bf16 bf16x8 __attribute__((ext_vector_type(8)));
typedef __bf16 bf16x4 __attribute__((ext_vector_type(4)));
typedef float f32x4 __attribute__((ext_vector_type(4)));

__device__ __forceinline__ void async_copy16(const void* g, void* l) {
  __builtin_amdgcn_global_load_lds(
      (const __attribute__((address_space(1))) void*)g,
      (__attribute__((address_space(3))) void*)l, 16, 0, 0);
}

// ---- fused fp32->bf16 conversion: x (4096 blocks) + Wcat (224 blocks) ----
__global__ __launch_bounds__(256) void conv_all(const float* __restrict__ x,
                                                const float* __restrict__ Wv,
                                                const float* __restrict__ Wk,
                                                const float* __restrict__ Wq,
                                                const float* __restrict__ Wa,
                                                __bf16* __restrict__ xb,
                                                __bf16* __restrict__ wcat) {
  if (blockIdx.x < 4096) {
    long i = ((long)blockIdx.x * 256 + threadIdx.x) * 8;
    float4 f0 = *(const float4*)(x + i);
    float4 f1 = *(const float4*)(x + i + 4);
    bf16x8 h;
    h[0] = (__bf16)f0.x; h[1] = (__bf16)f0.y; h[2] = (__bf16)f0.z; h[3] = (__bf16)f0.w;
    h[4] = (__bf16)f1.x; h[5] = (__bf16)f1.y; h[6] = (__bf16)f1.z; h[7] = (__bf16)f1.w;
    *(bf16x8*)(xb + i) = h;
  } else {
    long i = ((long)(blockIdx.x - 4096) * 256 + threadIdx.x) * 8;
    int row = (int)(i >> 9);
    int col = (int)(i & 511);
    const float* src;
    if (row < 512)      src = Wv + (long)row * 512 + col;
    else if (row < 640) src = Wk + (long)(row - 512) * 512 + col;
    else if (row < 768) src = Wq + (long)(row - 640) * 512 + col;
    else                src = Wa + (long)(row - 768) * 512 + col;
    float4 f0 = *(const float4*)(src);
    float4 f1 = *(const float4*)(src + 4);
    bf16x8 h;
    h[0] = (__bf16)f0.x; h[1] = (__bf16)f0.y; h[2] = (__bf16)f0.z; h[3] = (__bf16)f0.w;
    h[4] = (__bf16)f1.x; h[5] = (__bf16)f1.y; h[6] = (__bf16)f1.z; h[7] = (__bf16)f1.w;
    *(bf16x8*)(wcat + i) = h;
  }
}

// ---- K1: projection GEMM, bf16 MFMA. 1D grid 896, XCD-aware remap ----
// bid -> (mt, nt) with bid%8 == mt%8 (7 nt-blocks of one mt share an XCD).
// A: double-buffered LDS [128 rows][8 slots of 16B], phys slot =
// logical ^ (row&7), source pre-permuted, ONE __syncthreads per K-iter.
// B: direct global fragment gather (no staging).
__global__ __launch_bounds__(256) void proj_mfma(
    const __bf16* __restrict__ xb, const __bf16* __restrict__ wcat,
    const float* __restrict__ bv, const float* __restrict__ bk,
    const float* __restrict__ bq, const float* __restrict__ ba,
    __bf16* __restrict__ vt, __bf16* __restrict__ kout,
    __bf16* __restrict__ qout, float* __restrict__ aout) {
  __shared__ __attribute__((aligned(16))) char smem[128 * 136 * 2];
  __bf16* abuf0 = (__bf16*)smem;       // [128][64] = 16 KB
  __bf16* abuf1 = abuf0 + 128 * 64;    // second 16 KB
  __bf16* tr    = (__bf16*)smem;       // reused after K-loop (post-barrier)

  int tid = threadIdx.x;
  int lane = tid & 63, wave = tid >> 6;
  int bid = blockIdx.x;
  int xr = bid & 7, sq = bid >> 3;     // sq in 0..111
  int mt = xr + 8 * (sq / 7);
  int nt = sq % 7;
  int wr = wave >> 1, wcol = wave & 1;

  const __bf16* xtile = xb + (long)mt * 128 * 512;
  const __bf16* wtile = wcat + (long)nt * 128 * 512;

  f32x4 acc[4][4] = {};
  int lr8 = lane >> 3, lc8 = lane & 7;
  int l15 = lane & 15, qd = lane >> 4;
  int slsrc = (lc8 ^ lr8) * 8;
  int frd = l15 & 7;

  // prologue: stage first A tile into buf0
  {
#pragma unroll
    for (int h = 0; h < 4; ++h) {
      int q = wave * 4 + h;
      int row = q * 8 + lr8;
      async_copy16(xtile + (long)row * 512 + slsrc, &abuf0[q * 512]);
    }
  }
  __bf16* cur = abuf0;
  __bf16* nxt = abuf1;

  for (int it = 0; it < 8; ++it) {
    __syncthreads();                   // drains cur's stage; prev reads done
    if (it < 7) {
      int k0n = (it + 1) * 64;
#pragma unroll
      for (int h = 0; h < 4; ++h) {
        int q = wave * 4 + h;
        int row = q * 8 + lr8;
        async_copy16(xtile + (long)row * 512 + k0n + slsrc, &nxt[q * 512]);
      }
    }
    int k0 = it * 64;
#pragma unroll
    for (int kk = 0; kk < 2; ++kk) {
      bf16x8 af[4], bfr[4];
#pragma unroll
      for (int t = 0; t < 4; ++t) {
        int ra = wr * 64 + t * 16 + l15;
        int slot = ((kk * 4 + qd) ^ frd) * 8;
        af[t] = *(const bf16x8*)&cur[ra * 64 + slot];
        int rb = wcol * 64 + t * 16 + l15;
        bfr[t] = *(const bf16x8*)(wtile + (long)rb * 512 + k0 + kk * 32 + qd * 8);
      }
#pragma unroll
      for (int i = 0; i < 4; ++i)
#pragma unroll
        for (int j = 0; j < 4; ++j)
          acc[i][j] = __builtin_amdgcn_mfma_f32_16x16x32_bf16(af[i], bfr[j], acc[i][j], 0, 0, 0);
    }
    __bf16* tmp = cur; cur = nxt; nxt = tmp;
  }
  __syncthreads();                     // all reads done before tr overlay

  if (nt < 4) {
    const float* bias = bv + nt * 128;
#pragma unroll
    for (int i = 0; i < 4; ++i)
#pragma unroll
      for (int j = 0; j < 4; ++j) {
        int col = wcol * 64 + j * 16 + l15;
        float bz = bias[col];
#pragma unroll
        for (int r = 0; r < 4; ++r) {
          int row = wr * 64 + i * 16 + qd * 4 + r;   // row = t_l*8 + b
          tr[col * 136 + (row & 7) * 16 + (row >> 3)] = (__bf16)(acc[i][j][r] + bz);
        }
      }
    __syncthreads();
    int cbase = (mt >> 3) * 8;
    int s0 = (mt & 7) * 16;
#pragma unroll
    for (int it = 0; it < 4; ++it) {
      int p = it * 256 + tid;
      int d = p & 127, b = p >> 7;
      bf16x8 u0 = *(const bf16x8*)&tr[d * 136 + b * 16];
      bf16x8 u1 = *(const bf16x8*)&tr[d * 136 + b * 16 + 8];
      __bf16* dst = vt + ((long)(cbase + b) * 512 + nt * 128 + d) * 128 + s0;
      *(bf16x8*)dst = u0;
      *(bf16x8*)(dst + 8) = u1;
    }
    return;
  }

  const float* bias; bool sig = false;
  __bf16* dstb = nullptr; float* dstf = nullptr;
  if (nt == 4)      { bias = bk; dstb = kout; }
  else if (nt == 5) { bias = bq; dstb = qout; }
  else              { bias = ba; dstf = aout; sig = true; }

#pragma unroll
  for (int i = 0; i < 4; ++i)
#pragma unroll
    for (int j = 0; j < 4; ++j) {
      int col = wcol * 64 + j * 16 + l15;
      float bz = bias[col];
#pragma unroll
      for (int r = 0; r < 4; ++r) {
        int row = wr * 64 + i * 16 + qd * 4 + r;
        float z = acc[i][j][r] + bz;
        long addr = ((long)mt * 128 + row) * 128 + col;
        if (sig) dstf[addr] = 1.f / (1.f + __expf(-z));
        else     dstb[addr] = (__bf16)z;
      }
    }
}

// ---- scan_cp: SEGMENTED cumprod scan (R6) ----
__global__ __launch_bounds__(512) void scan_cp(const float* __restrict__ a,
                                               const __bf16* __restrict__ k,
                                               const __bf16* __restrict__ q,
                                               __bf16* __restrict__ kbs,
                                               __bf16* __restrict__ qb,
                                               __bf16* __restrict__ kt,
                                               float* __restrict__ cpend) {
  __shared__ float segprod[8][64];
  int tid = threadIdx.x;
  int nl = tid & 63;
  int seg = tid >> 6;
  int bid = blockIdx.x;
  int nh = bid & 1;
  int b = (bid >> 1) & 7;
  int c = bid >> 4;
  int n = nh * 64 + nl;
  long base = ((long)c * 1024 + b) * 128 + n;
  int t0 = seg * 16;

  float av[16];
  float p = 1.f;
#pragma unroll
  for (int i = 0; i < 16; ++i) {
    float v = fmaxf(a[base + (long)(t0 + i) * 1024], EPSV);
    av[i] = v;
    p *= v;
  }
  segprod[seg][nl] = p;
  __syncthreads();

  float prefix = 1.f;
#pragma unroll
  for (int s = 0; s < 7; ++s)
    if (s < seg) prefix *= segprod[s][nl];
  if (seg == 7) cpend[(c * 8 + b) * 128 + n] = prefix * p;

  float cp = prefix;
  __bf16 ktbuf[16];
#pragma unroll
  for (int i = 0; i < 16; ++i) {
    long off = base + (long)(t0 + i) * 1024;
    cp *= av[i];
    float kk = (float)k[off] / (cp + EPSV);
    float qq = (float)q[off] * cp;
    __bf16 kh = (__bf16)kk;
    kbs[off] = kh;
    qb[off] = (__bf16)qq;
    ktbuf[i] = kh;
  }
  __bf16* dst = kt + ((long)((c * 8 + b) * 128 + n)) * 128 + t0;
#pragma unroll
  for (int i = 0; i < 2; ++i) {
    bf16x8 h;
#pragma unroll
    for (int j = 0; j < 8; ++j) h[j] = ktbuf[i * 8 + j];
    *(bf16x8*)(dst + i * 8) = h;
  }
}

// ---- gmm: Gt[d,n] = cpend[n] * sum_s vt[d,s]*kt[n,s].  grid 512 = cb*4+dt ----
__global__ __launch_bounds__(256) void gmm(const __bf16* __restrict__ vt,
                                           const __bf16* __restrict__ kt,
                                           const float* __restrict__ cpend,
                                           __bf16* __restrict__ Gt) {
  __shared__ __attribute__((aligned(16))) __bf16 v_sm[128 * 128];
  __shared__ __attribute__((aligned(16))) __bf16 k_sm[128 * 128];
  int tid = threadIdx.x, lane = tid & 63, wave = tid >> 6;
  int wr = wave >> 1, wc = wave & 1;
  int l15 = lane & 15, qd = lane >> 4;
  int cb = blockIdx.x >> 2, dt = blockIdx.x & 3;
  const __bf16* vbase = vt + ((long)cb * 512 + dt * 128) * 128;
  const __bf16* kbase = kt + (long)cb * 16384;

  int rowoff = lane >> 4, sl = lane & 15;
#pragma unroll
  for (int it = 0; it < 8; ++it) {
    int rbase = it * 16 + wave * 4;
    int row = rbase + rowoff;
    int sg = (sl ^ (row & 15)) * 8;
    async_copy16(vbase + (long)row * 128 + sg, &v_sm[rbase * 128]);
    async_copy16(kbase + (long)row * 128 + sg, &k_sm[rbase * 128]);
  }
  __syncthreads();

  f32x4 acc[4][4] = {};
#pragma unroll
  for (int kk = 0; kk < 4; ++kk) {
    bf16x8 af[4], bfr[4];
#pragma unroll
    for (int i = 0; i < 4; ++i) {
      int ra = wr * 64 + i * 16 + l15;
      af[i] = *(const bf16x8*)&v_sm[ra * 128 + (((kk * 4 + qd) ^ l15) & 15) * 8];
    }
#pragma unroll
    for (int j = 0; j < 4; ++j) {
      int rb = wc * 64 + j * 16 + l15;
      bfr[j] = *(const bf16x8*)&k_sm[rb * 128 + (((kk * 4 + qd) ^ l15) & 15) * 8];
    }
#pragma unroll
    for (int i = 0; i < 4; ++i)
#pragma unroll
      for (int j = 0; j < 4; ++j)
        acc[i][j] = __builtin_amdgcn_mfma_f32_16x16x32_bf16(af[i], bfr[j], acc[i][j], 0, 0, 0);
  }
  float ce[4];
#pragma unroll
  for (int j = 0; j < 4; ++j) ce[j] = cpend[cb * 128 + wc * 64 + j * 16 + l15];
#pragma unroll
  for (int i = 0; i < 4; ++i)
#pragma unroll
    for (int j = 0; j < 4; ++j) {
      int col = wc * 64 + j * 16 + l15;
#pragma unroll
      for (int r = 0; r < 4; ++r) {
        int row = wr * 64 + i * 16 + qd * 4 + r;
        Gt[((long)cb * 512 + dt * 128 + row) * 128 + col] = (__bf16)(acc[i][j][r] * ce[j]);
      }
    }
}

// ---- scan_state: fp32 scan over chunks on Gt(bf16); emits St bf16 ----
__global__ __launch_bounds__(256) void scan_state(const __bf16* __restrict__ Gt,
                                                  const float* __restrict__ cpend,
                                                  __bf16* __restrict__ St) {
  long e = ((long)blockIdx.x * 256 + threadIdx.x) * 4;
  int n0 = (int)(e & 127);
  int b = (int)(e >> 16);
  float4 S = {0.f, 0.f, 0.f, 0.f};
#pragma unroll
  for (int c = 0; c < 16; ++c) {
    long idx = (long)c * 524288 + e;
    bf16x4 g = *(const bf16x4*)(Gt + idx);
    bf16x4 sv;
    sv[0] = (__bf16)S.x; sv[1] = (__bf16)S.y;
    sv[2] = (__bf16)S.z; sv[3] = (__bf16)S.w;
    *(bf16x4*)(St + idx) = sv;
    const float4 cp = *(const float4*)(cpend + (c * 8 + b) * 128 + n0);
    S.x = (float)g[0] + S.x * cp.x;
    S.y = (float)g[1] + S.y * cp.y;
    S.z = (float)g[2] + S.z * cp.z;
    S.w = (float)g[3] + S.w * cp.w;
  }
}

// ---- ymm: y^T[d,t] = sum_s vt[d,s]*A[t,s] + sum_n St[d,n]*qb[t,n] ----
// HYBRID (R13): q_sm staged (read twice: P1 af, P3 bfr) + A_lds; kbs/vt/St
// direct global. LDS 67.6 KB -> 2 blocks/CU.
__global__ __launch_bounds__(256) void ymm(const __bf16* __restrict__ qb,
                                           const __bf16* __restrict__ kbs,
                                           const __bf16* __restrict__ vt,
                                           const __bf16* __restrict__ St,
                                           float* __restrict__ out) {
  __shared__ __attribute__((aligned(16))) __bf16 q_sm[128 * 128];   // 32 KB
  __shared__ __attribute__((aligned(16))) __bf16 A_lds[128 * 136];  // 34.8 KB
  int tid = threadIdx.x, lane = tid & 63, wave = tid >> 6;
  int wr = wave >> 1, wc = wave & 1;
  int l15 = lane & 15, qd = lane >> 4;
  int cb = blockIdx.x >> 2, dt = blockIdx.x & 3;
  int c = cb >> 3, b = cb & 7;
  const __bf16* qg = qb + ((long)c * 1024 + b) * 128;   // row stride 1024 elems
  const __bf16* kg = kbs + ((long)c * 1024 + b) * 128;
  const __bf16* vbase = vt + ((long)cb * 512 + dt * 128) * 128;  // contiguous
  const __bf16* sbase = St + ((long)cb * 512 + dt * 128) * 128;
  int rowoff = lane >> 4, sl = lane & 15;

#pragma unroll
  for (int it = 0; it < 8; ++it) {
    int rbase = it * 16 + wave * 4;
    int row = rbase + rowoff;
    int sg = (sl ^ (row & 15)) * 8;
    async_copy16(qg + (long)row * 1024 + sg, &q_sm[rbase * 128]);
  }
  __syncthreads();

  {
    f32x4 accA[4][4] = {};
#pragma unroll
    for (int kk = 0; kk < 4; ++kk) {
      int k0 = kk * 32;
      bf16x8 af[4], bfr[4];
#pragma unroll
      for (int i = 0; i < 4; ++i) {
        int ra = wr * 64 + i * 16 + l15;
        af[i] = *(const bf16x8*)&q_sm[ra * 128 + (((kk * 4 + qd) ^ l15) & 15) * 8];
      }
#pragma unroll
      for (int j = 0; j < 4; ++j) {
        int rb = wc * 64 + j * 16 + l15;
        bfr[j] = *(const bf16x8*)(kg + (long)rb * 1024 + k0 + qd * 8);
      }
#pragma unroll
      for (int i = 0; i < 4; ++i)
#pragma unroll
        for (int j = 0; j < 4; ++j)
          accA[i][j] = __builtin_amdgcn_mfma_f32_16x16x32_bf16(af[i], bfr[j], accA[i][j], 0, 0, 0);
    }
#pragma unroll
    for (int i = 0; i < 4; ++i)
#pragma unroll
      for (int j = 0; j < 4; ++j) {
        int s = wc * 64 + j * 16 + l15;
#pragma unroll
        for (int r = 0; r < 4; ++r) {
          int t = wr * 64 + i * 16 + qd * 4 + r;
          A_lds[t * 136 + s] = (s <= t) ? (__bf16)accA[i][j][r] : (__bf16)0.f;
        }
      }
  }
  __syncthreads();   // A visible

  f32x4 acc[4][4] = {};
#pragma unroll
  for (int kk = 0; kk < 4; ++kk) {
    int k0 = kk * 32;
    bf16x8 af[4], bfr[4];
#pragma unroll
    for (int i = 0; i < 4; ++i) {
      int ra = wr * 64 + i * 16 + l15;
      af[i] = *(const bf16x8*)(vbase + (long)ra * 128 + k0 + qd * 8);
    }
#pragma unroll
    for (int j = 0; j < 4; ++j)
      bfr[j] = *(const bf16x8*)&A_lds[(wc * 64 + j * 16 + l15) * 136 + k0 + qd * 8];
#pragma unroll
    for (int i = 0; i < 4; ++i)
#pragma unroll
      for (int j = 0; j < 4; ++j)
        acc[i][j] = __builtin_amdgcn_mfma_f32_16x16x32_bf16(af[i], bfr[j], acc[i][j], 0, 0, 0);
  }

#pragma unroll
  for (int kk = 0; kk < 4; ++kk) {
    int k0 = kk * 32;
    bf16x8 af[4], bfr[4];
#pragma unroll
    for (int i = 0; i < 4; ++i) {
      int ra = wr * 64 + i * 16 + l15;
      af[i] = *(const bf16x8*)(sbase + (long)ra * 128 + k0 + qd * 8);
    }
#pragma unroll
    for (int j = 0; j < 4; ++j) {
      int rb = wc * 64 + j * 16 + l15;
      bfr[j] = *(const bf16x8*)&q_sm[rb * 128 + (((kk * 4 + qd) ^ l15) & 15) * 8];
    }
#pragma unroll
    for (int i = 0; i < 4; ++i)
#pragma unroll
      for (int j = 0; j < 4; ++j)
        acc[i][j] = __builtin_amdgcn_mfma_f32_16x16x32_bf16(af[i], bfr[j], acc[i][j], 0, 0, 0);
  }

#pragma unroll
  for (int i = 0; i < 4; ++i)
#pragma unroll
    for (int j = 0; j < 4; ++j) {
      int colt = wc * 64 + j * 16 + l15;
      long addr = ((long)(c * 128 + colt) * 8 + b) * 512 + dt * 128 + wr * 64 + i * 16 + qd * 4;
      *(float4*)(out + addr) = *(float4*)&acc[i][j];
    }
}

extern "C" void kernel_launch(void* const* d_in, const int* in_sizes, int n_in,
                              void* d_out, int out_size, void* d_ws, size_t ws_size,
                              hipStream_t stream) {
  const float* x  = (const float*)d_in[0];
  const float* Wv = (const float*)d_in[1];
  const float* bv = (const float*)d_in[2];
  const float* Wk = (const float*)d_in[3];
  const float* bk = (const float*)d_in[4];
  const float* Wq = (const float*)d_in[5];
  const float* bq = (const float*)d_in[6];
  const float* Wa = (const float*)d_in[7];
  const float* ba = (const float*)d_in[8];
  float* out = (float*)d_out;
  float* ws = (float*)d_ws;

  float*  a_buf = ws;                          // 2,097,152 fl
  __bf16* qb    = (__bf16*)(ws + 2097152);     // 2,097,152 bf
  __bf16* kbs   = (__bf16*)(ws + 3145728);     // 2,097,152 bf
  __bf16* kt    = (__bf16*)(ws + 4194304);     // 2,097,152 bf
  __bf16* vt    = (__bf16*)(ws + 5242880);     // 8,388,608 bf
  __bf16* k_raw = (__bf16*)(ws + 9437184);     // 2,097,152 bf
  __bf16* q_raw = (__bf16*)(ws + 10485760);    // 2,097,152 bf
  __bf16* xb    = (__bf16*)(ws + 11534336);    // 8,388,608 bf
  __bf16* Wcat  = (__bf16*)(ws + 15728640);    // 458,752 bf
  __bf16* Gt    = xb;                          // overlay: xb dead after proj
  __bf16* St    = (__bf16*)(ws + 15958016);    // 8,388,608 bf
  float*  cpend = ws + 20152320;               // 16,384 fl

  conv_all<<<4320, 256, 0, stream>>>(x, Wv, Wk, Wq, Wa, xb, Wcat);
  proj_mfma<<<896, 256, 0, stream>>>(xb, Wcat, bv, bk, bq, ba,
                                     vt, k_raw, q_raw, a_buf);
  scan_cp<<<256, 512, 0, stream>>>(a_buf, k_raw, q_raw, kbs, qb, kt, cpend);
  gmm<<<512, 256, 0, stream>>>(vt, kt, cpend, Gt);
  scan_state<<<512, 256, 0, stream>>>(Gt, cpend, St);
  ymm<<<512, 256, 0, stream>>>(qb, kbs, vt, St, out);
}

// Round 13
// 173.032 us; speedup vs baseline: 1.0871x; 1.0871x over previous
//
#include <hip/hip_runtime.h>

// GLA forward, chunked. T=2048, B=8, IN=512, DV=512, NK=128, CHUNK=128, NCH=16.
// Round 17: REVERT to R15 (= R13 structure; best verified 173.6-174.1us).
// R16's A-dbuf + B-direct-gather regressed to 188 (B fragment gathers at 1KB
// stride put scattered vmcnt latency on the critical path). proj ceiling
// statement: floor 10.5us (66MB HBM) + barrier-drain structure = ~42us
// measured; counted-vmcnt is the only remaining fix and raced in R8 (not
// race-screenable headless). System: fills ~87 + conv 15.2 (HBM roofline) +
// proj ~42 + back-four ~30 (~1.3x floors) + gaps = ~174us practical ceiling.
//
// Layouts (cb = c*8+b, r = t_glob*8+b):
//   a_buf  fp32 [r][128]
//   k_raw/q_raw bf16 [r][128]
//   qb/kbs bf16 [r][128]          (q~ = q*cp, k~ = k/(cp+eps))
//   kt     bf16 [cb*128 + n][s]   (k~ transposed)
//   vt     bf16 [cb*512 + d][s]
//   Gt     bf16 [cb*512 + d][n]   (scan input, overlays xb)
//   St     bf16 [cb*512 + d][n]   (S_prev per chunk)

#define EPSV 1e-8f

typedef __bf16 bf16x8 __attribute__((ext_vector_type(8)));
typedef __bf16 bf16x4 __attribute__((ext_vector_type(4)));
typedef float f32x4 __attribute__((ext_vector_type(4)));

__device__ __forceinline__ void async_copy16(const void* g, void* l) {
  __builtin_amdgcn_global_load_lds(
      (const __attribute__((address_space(1))) void*)g,
      (__attribute__((address_space(3))) void*)l, 16, 0, 0);
}

// ---- fused fp32->bf16 conversion: x (4096 blocks) + Wcat (224 blocks) ----
__global__ __launch_bounds__(256) void conv_all(const float* __restrict__ x,
                                                const float* __restrict__ Wv,
                                                const float* __restrict__ Wk,
                                                const float* __restrict__ Wq,
                                                const float* __restrict__ Wa,
                                                __bf16* __restrict__ xb,
                                                __bf16* __restrict__ wcat) {
  if (blockIdx.x < 4096) {
    long i = ((long)blockIdx.x * 256 + threadIdx.x) * 8;
    float4 f0 = *(const float4*)(x + i);
    float4 f1 = *(const float4*)(x + i + 4);
    bf16x8 h;
    h[0] = (__bf16)f0.x; h[1] = (__bf16)f0.y; h[2] = (__bf16)f0.z; h[3] = (__bf16)f0.w;
    h[4] = (__bf16)f1.x; h[5] = (__bf16)f1.y; h[6] = (__bf16)f1.z; h[7] = (__bf16)f1.w;
    *(bf16x8*)(xb + i) = h;
  } else {
    long i = ((long)(blockIdx.x - 4096) * 256 + threadIdx.x) * 8;
    int row = (int)(i >> 9);
    int col = (int)(i & 511);
    const float* src;
    if (row < 512)      src = Wv + (long)row * 512 + col;
    else if (row < 640) src = Wk + (long)(row - 512) * 512 + col;
    else if (row < 768) src = Wq + (long)(row - 640) * 512 + col;
    else                src = Wa + (long)(row - 768) * 512 + col;
    float4 f0 = *(const float4*)(src);
    float4 f1 = *(const float4*)(src + 4);
    bf16x8 h;
    h[0] = (__bf16)f0.x; h[1] = (__bf16)f0.y; h[2] = (__bf16)f0.z; h[3] = (__bf16)f0.w;
    h[4] = (__bf16)f1.x; h[5] = (__bf16)f1.y; h[6] = (__bf16)f1.z; h[7] = (__bf16)f1.w;
    *(bf16x8*)(wcat + i) = h;
  }
}

// ---- K1: projection GEMM, bf16 MFMA. 1D grid 896, XCD-aware remap ----
// bid -> (mt, nt) with bid%8 == mt%8 (7 nt-blocks of one mt share an XCD).
// BK=64: [128 rows][8 slots of 16B], phys slot = logical ^ (row&7), source
// pre-permuted. 8 K-iterations, plain __syncthreads. global_load_lds staging.
__global__ __launch_bounds__(256) void proj_mfma(
    const __bf16* __restrict__ xb, const __bf16* __restrict__ wcat,
    const float* __restrict__ bv, const float* __restrict__ bk,
    const float* __restrict__ bq, const float* __restrict__ ba,
    __bf16* __restrict__ vt, __bf16* __restrict__ kout,
    __bf16* __restrict__ qout, float* __restrict__ aout) {
  __shared__ __attribute__((aligned(16))) char smem[128 * 136 * 2];
  __bf16* a_sm = (__bf16*)smem;        // [128][64]
  __bf16* b_sm = a_sm + 128 * 64;
  __bf16* tr   = (__bf16*)smem;        // reused after K-loop (post-barrier)

  int tid = threadIdx.x;
  int lane = tid & 63, wave = tid >> 6;
  int bid = blockIdx.x;
  int xr = bid & 7, sq = bid >> 3;     // sq in 0..111
  int mt = xr + 8 * (sq / 7);
  int nt = sq % 7;
  int wr = wave >> 1, wcol = wave & 1;

  const __bf16* xtile = xb + (long)mt * 128 * 512;
  const __bf16* wtile = wcat + (long)nt * 128 * 512;

  f32x4 acc[4][4] = {};
  int lr8 = lane >> 3, lc8 = lane & 7;
  int l15 = lane & 15, qd = lane >> 4;
  int slsrc = (lc8 ^ lr8) * 8;
  int frd = l15 & 7;

  for (int k0 = 0; k0 < 512; k0 += 64) {
#pragma unroll
    for (int h = 0; h < 4; ++h) {
      int q = wave * 4 + h;
      int row = q * 8 + lr8;
      async_copy16(xtile + (long)row * 512 + k0 + slsrc, &a_sm[q * 512]);
      async_copy16(wtile + (long)row * 512 + k0 + slsrc, &b_sm[q * 512]);
    }
    __syncthreads();
#pragma unroll
    for (int kk = 0; kk < 2; ++kk) {
      bf16x8 af[4], bfr[4];
#pragma unroll
      for (int t = 0; t < 4; ++t) {
        int ra = wr * 64 + t * 16 + l15;
        int rb = wcol * 64 + t * 16 + l15;
        int slot = ((kk * 4 + qd) ^ frd) * 8;
        af[t]  = *(const bf16x8*)&a_sm[ra * 64 + slot];
        bfr[t] = *(const bf16x8*)&b_sm[rb * 64 + slot];
      }
#pragma unroll
      for (int i = 0; i < 4; ++i)
#pragma unroll
        for (int j = 0; j < 4; ++j)
          acc[i][j] = __builtin_amdgcn_mfma_f32_16x16x32_bf16(af[i], bfr[j], acc[i][j], 0, 0, 0);
    }
    __syncthreads();
  }

  if (nt < 4) {
    const float* bias = bv + nt * 128;
#pragma unroll
    for (int i = 0; i < 4; ++i)
#pragma unroll
      for (int j = 0; j < 4; ++j) {
        int col = wcol * 64 + j * 16 + l15;
        float bz = bias[col];
#pragma unroll
        for (int r = 0; r < 4; ++r) {
          int row = wr * 64 + i * 16 + qd * 4 + r;   // row = t_l*8 + b
          tr[col * 136 + (row & 7) * 16 + (row >> 3)] = (__bf16)(acc[i][j][r] + bz);
        }
      }
    __syncthreads();
    int cbase = (mt >> 3) * 8;
    int s0 = (mt & 7) * 16;
#pragma unroll
    for (int it = 0; it < 4; ++it) {
      int p = it * 256 + tid;
      int d = p & 127, b = p >> 7;
      bf16x8 u0 = *(const bf16x8*)&tr[d * 136 + b * 16];
      bf16x8 u1 = *(const bf16x8*)&tr[d * 136 + b * 16 + 8];
      __bf16* dst = vt + ((long)(cbase + b) * 512 + nt * 128 + d) * 128 + s0;
      *(bf16x8*)dst = u0;
      *(bf16x8*)(dst + 8) = u1;
    }
    return;
  }

  const float* bias; bool sig = false;
  __bf16* dstb = nullptr; float* dstf = nullptr;
  if (nt == 4)      { bias = bk; dstb = kout; }
  else if (nt == 5) { bias = bq; dstb = qout; }
  else              { bias = ba; dstf = aout; sig = true; }

#pragma unroll
  for (int i = 0; i < 4; ++i)
#pragma unroll
    for (int j = 0; j < 4; ++j) {
      int col = wcol * 64 + j * 16 + l15;
      float bz = bias[col];
#pragma unroll
      for (int r = 0; r < 4; ++r) {
        int row = wr * 64 + i * 16 + qd * 4 + r;
        float z = acc[i][j][r] + bz;
        long addr = ((long)mt * 128 + row) * 128 + col;
        if (sig) dstf[addr] = 1.f / (1.f + __expf(-z));
        else     dstb[addr] = (__bf16)z;
      }
    }
}

// ---- scan_cp: SEGMENTED cumprod scan (R6) ----
__global__ __launch_bounds__(512) void scan_cp(const float* __restrict__ a,
                                               const __bf16* __restrict__ k,
                                               const __bf16* __restrict__ q,
                                               __bf16* __restrict__ kbs,
                                               __bf16* __restrict__ qb,
                                               __bf16* __restrict__ kt,
                                               float* __restrict__ cpend) {
  __shared__ float segprod[8][64];
  int tid = threadIdx.x;
  int nl = tid & 63;
  int seg = tid >> 6;
  int bid = blockIdx.x;
  int nh = bid & 1;
  int b = (bid >> 1) & 7;
  int c = bid >> 4;
  int n = nh * 64 + nl;
  long base = ((long)c * 1024 + b) * 128 + n;
  int t0 = seg * 16;

  float av[16];
  float p = 1.f;
#pragma unroll
  for (int i = 0; i < 16; ++i) {
    float v = fmaxf(a[base + (long)(t0 + i) * 1024], EPSV);
    av[i] = v;
    p *= v;
  }
  segprod[seg][nl] = p;
  __syncthreads();

  float prefix = 1.f;
#pragma unroll
  for (int s = 0; s < 7; ++s)
    if (s < seg) prefix *= segprod[s][nl];
  if (seg == 7) cpend[(c * 8 + b) * 128 + n] = prefix * p;

  float cp = prefix;
  __bf16 ktbuf[16];
#pragma unroll
  for (int i = 0; i < 16; ++i) {
    long off = base + (long)(t0 + i) * 1024;
    cp *= av[i];
    float kk = (float)k[off] / (cp + EPSV);
    float qq = (float)q[off] * cp;
    __bf16 kh = (__bf16)kk;
    kbs[off] = kh;
    qb[off] = (__bf16)qq;
    ktbuf[i] = kh;
  }
  __bf16* dst = kt + ((long)((c * 8 + b) * 128 + n)) * 128 + t0;
#pragma unroll
  for (int i = 0; i < 2; ++i) {
    bf16x8 h;
#pragma unroll
    for (int j = 0; j < 8; ++j) h[j] = ktbuf[i * 8 + j];
    *(bf16x8*)(dst + i * 8) = h;
  }
}

// ---- gmm: Gt[d,n] = cpend[n] * sum_s vt[d,s]*kt[n,s].  grid 512 = cb*4+dt ----
__global__ __launch_bounds__(256) void gmm(const __bf16* __restrict__ vt,
                                           const __bf16* __restrict__ kt,
                                           const float* __restrict__ cpend,
                                           __bf16* __restrict__ Gt) {
  __shared__ __attribute__((aligned(16))) __bf16 v_sm[128 * 128];
  __shared__ __attribute__((aligned(16))) __bf16 k_sm[128 * 128];
  int tid = threadIdx.x, lane = tid & 63, wave = tid >> 6;
  int wr = wave >> 1, wc = wave & 1;
  int l15 = lane & 15, qd = lane >> 4;
  int cb = blockIdx.x >> 2, dt = blockIdx.x & 3;
  const __bf16* vbase = vt + ((long)cb * 512 + dt * 128) * 128;
  const __bf16* kbase = kt + (long)cb * 16384;

  int rowoff = lane >> 4, sl = lane & 15;
#pragma unroll
  for (int it = 0; it < 8; ++it) {
    int rbase = it * 16 + wave * 4;
    int row = rbase + rowoff;
    int sg = (sl ^ (row & 15)) * 8;
    async_copy16(vbase + (long)row * 128 + sg, &v_sm[rbase * 128]);
    async_copy16(kbase + (long)row * 128 + sg, &k_sm[rbase * 128]);
  }
  __syncthreads();

  f32x4 acc[4][4] = {};
#pragma unroll
  for (int kk = 0; kk < 4; ++kk) {
    bf16x8 af[4], bfr[4];
#pragma unroll
    for (int i = 0; i < 4; ++i) {
      int ra = wr * 64 + i * 16 + l15;
      af[i] = *(const bf16x8*)&v_sm[ra * 128 + (((kk * 4 + qd) ^ l15) & 15) * 8];
    }
#pragma unroll
    for (int j = 0; j < 4; ++j) {
      int rb = wc * 64 + j * 16 + l15;
      bfr[j] = *(const bf16x8*)&k_sm[rb * 128 + (((kk * 4 + qd) ^ l15) & 15) * 8];
    }
#pragma unroll
    for (int i = 0; i < 4; ++i)
#pragma unroll
      for (int j = 0; j < 4; ++j)
        acc[i][j] = __builtin_amdgcn_mfma_f32_16x16x32_bf16(af[i], bfr[j], acc[i][j], 0, 0, 0);
  }
  float ce[4];
#pragma unroll
  for (int j = 0; j < 4; ++j) ce[j] = cpend[cb * 128 + wc * 64 + j * 16 + l15];
#pragma unroll
  for (int i = 0; i < 4; ++i)
#pragma unroll
    for (int j = 0; j < 4; ++j) {
      int col = wc * 64 + j * 16 + l15;
#pragma unroll
      for (int r = 0; r < 4; ++r) {
        int row = wr * 64 + i * 16 + qd * 4 + r;
        Gt[((long)cb * 512 + dt * 128 + row) * 128 + col] = (__bf16)(acc[i][j][r] * ce[j]);
      }
    }
}

// ---- scan_state: fp32 scan over chunks on Gt(bf16); emits St bf16 ----
__global__ __launch_bounds__(256) void scan_state(const __bf16* __restrict__ Gt,
                                                  const float* __restrict__ cpend,
                                                  __bf16* __restrict__ St) {
  long e = ((long)blockIdx.x * 256 + threadIdx.x) * 4;
  int n0 = (int)(e & 127);
  int b = (int)(e >> 16);
  float4 S = {0.f, 0.f, 0.f, 0.f};
#pragma unroll
  for (int c = 0; c < 16; ++c) {
    long idx = (long)c * 524288 + e;
    bf16x4 g = *(const bf16x4*)(Gt + idx);
    bf16x4 sv;
    sv[0] = (__bf16)S.x; sv[1] = (__bf16)S.y;
    sv[2] = (__bf16)S.z; sv[3] = (__bf16)S.w;
    *(bf16x4*)(St + idx) = sv;
    const float4 cp = *(const float4*)(cpend + (c * 8 + b) * 128 + n0);
    S.x = (float)g[0] + S.x * cp.x;
    S.y = (float)g[1] + S.y * cp.y;
    S.z = (float)g[2] + S.z * cp.z;
    S.w = (float)g[3] + S.w * cp.w;
  }
}

// ---- ymm: y^T[d,t] = sum_s vt[d,s]*A[t,s] + sum_n St[d,n]*qb[t,n] ----
// HYBRID (R13): q_sm staged (read twice: P1 af, P3 bfr) + A_lds; kbs/vt/St
// direct global. LDS 67.6 KB -> 2 blocks/CU.
__global__ __launch_bounds__(256) void ymm(const __bf16* __restrict__ qb,
                                           const __bf16* __restrict__ kbs,
                                           const __bf16* __restrict__ vt,
                                           const __bf16* __restrict__ St,
                                           float* __restrict__ out) {
  __shared__ __attribute__((aligned(16))) __bf16 q_sm[128 * 128];   // 32 KB
  __shared__ __attribute__((aligned(16))) __bf16 A_lds[128 * 136];  // 34.8 KB
  int tid = threadIdx.x, lane = tid & 63, wave = tid >> 6;
  int wr = wave >> 1, wc = wave & 1;
  int l15 = lane & 15, qd = lane >> 4;
  int cb = blockIdx.x >> 2, dt = blockIdx.x & 3;
  int c = cb >> 3, b = cb & 7;
  const __bf16* qg = qb + ((long)c * 1024 + b) * 128;   // row stride 1024 elems
  const __bf16* kg = kbs + ((long)c * 1024 + b) * 128;
  const __bf16* vbase = vt + ((long)cb * 512 + dt * 128) * 128;  // contiguous
  const __bf16* sbase = St + ((long)cb * 512 + dt * 128) * 128;
  int rowoff = lane >> 4, sl = lane & 15;

#pragma unroll
  for (int it = 0; it < 8; ++it) {
    int rbase = it * 16 + wave * 4;
    int row = rbase + rowoff;
    int sg = (sl ^ (row & 15)) * 8;
    async_copy16(qg + (long)row * 1024 + sg, &q_sm[rbase * 128]);
  }
  __syncthreads();

  {
    f32x4 accA[4][4] = {};
#pragma unroll
    for (int kk = 0; kk < 4; ++kk) {
      int k0 = kk * 32;
      bf16x8 af[4], bfr[4];
#pragma unroll
      for (int i = 0; i < 4; ++i) {
        int ra = wr * 64 + i * 16 + l15;
        af[i] = *(const bf16x8*)&q_sm[ra * 128 + (((kk * 4 + qd) ^ l15) & 15) * 8];
      }
#pragma unroll
      for (int j = 0; j < 4; ++j) {
        int rb = wc * 64 + j * 16 + l15;
        bfr[j] = *(const bf16x8*)(kg + (long)rb * 1024 + k0 + qd * 8);
      }
#pragma unroll
      for (int i = 0; i < 4; ++i)
#pragma unroll
        for (int j = 0; j < 4; ++j)
          accA[i][j] = __builtin_amdgcn_mfma_f32_16x16x32_bf16(af[i], bfr[j], accA[i][j], 0, 0, 0);
    }
#pragma unroll
    for (int i = 0; i < 4; ++i)
#pragma unroll
      for (int j = 0; j < 4; ++j) {
        int s = wc * 64 + j * 16 + l15;
#pragma unroll
        for (int r = 0; r < 4; ++r) {
          int t = wr * 64 + i * 16 + qd * 4 + r;
          A_lds[t * 136 + s] = (s <= t) ? (__bf16)accA[i][j][r] : (__bf16)0.f;
        }
      }
  }
  __syncthreads();   // A visible

  f32x4 acc[4][4] = {};
#pragma unroll
  for (int kk = 0; kk < 4; ++kk) {
    int k0 = kk * 32;
    bf16x8 af[4], bfr[4];
#pragma unroll
    for (int i = 0; i < 4; ++i) {
      int ra = wr * 64 + i * 16 + l15;
      af[i] = *(const bf16x8*)(vbase + (long)ra * 128 + k0 + qd * 8);
    }
#pragma unroll
    for (int j = 0; j < 4; ++j)
      bfr[j] = *(const bf16x8*)&A_lds[(wc * 64 + j * 16 + l15) * 136 + k0 + qd * 8];
#pragma unroll
    for (int i = 0; i < 4; ++i)
#pragma unroll
      for (int j = 0; j < 4; ++j)
        acc[i][j] = __builtin_amdgcn_mfma_f32_16x16x32_bf16(af[i], bfr[j], acc[i][j], 0, 0, 0);
  }

#pragma unroll
  for (int kk = 0; kk < 4; ++kk) {
    int k0 = kk * 32;
    bf16x8 af[4], bfr[4];
#pragma unroll
    for (int i = 0; i < 4; ++i) {
      int ra = wr * 64 + i * 16 + l15;
      af[i] = *(const bf16x8*)(sbase + (long)ra * 128 + k0 + qd * 8);
    }
#pragma unroll
    for (int j = 0; j < 4; ++j) {
      int rb = wc * 64 + j * 16 + l15;
      bfr[j] = *(const bf16x8*)&q_sm[rb * 128 + (((kk * 4 + qd) ^ l15) & 15) * 8];
    }
#pragma unroll
    for (int i = 0; i < 4; ++i)
#pragma unroll
      for (int j = 0; j < 4; ++j)
        acc[i][j] = __builtin_amdgcn_mfma_f32_16x16x32_bf16(af[i], bfr[j], acc[i][j], 0, 0, 0);
  }

#pragma unroll
  for (int i = 0; i < 4; ++i)
#pragma unroll
    for (int j = 0; j < 4; ++j) {
      int colt = wc * 64 + j * 16 + l15;
      long addr = ((long)(c * 128 + colt) * 8 + b) * 512 + dt * 128 + wr * 64 + i * 16 + qd * 4;
      *(float4*)(out + addr) = *(float4*)&acc[i][j];
    }
}

extern "C" void kernel_launch(void* const* d_in, const int* in_sizes, int n_in,
                              void* d_out, int out_size, void* d_ws, size_t ws_size,
                              hipStream_t stream) {
  const float* x  = (const float*)d_in[0];
  const float* Wv = (const float*)d_in[1];
  const float* bv = (const float*)d_in[2];
  const float* Wk = (const float*)d_in[3];
  const float* bk = (const float*)d_in[4];
  const float* Wq = (const float*)d_in[5];
  const float* bq = (const float*)d_in[6];
  const float* Wa = (const float*)d_in[7];
  const float* ba = (const float*)d_in[8];
  float* out = (float*)d_out;
  float* ws = (float*)d_ws;

  float*  a_buf = ws;                          // 2,097,152 fl
  __bf16* qb    = (__bf16*)(ws + 2097152);     // 2,097,152 bf
  __bf16* kbs   = (__bf16*)(ws + 3145728);     // 2,097,152 bf
  __bf16* kt    = (__bf16*)(ws + 4194304);     // 2,097,152 bf
  __bf16* vt    = (__bf16*)(ws + 5242880);     // 8,388,608 bf
  __bf16* k_raw = (__bf16*)(ws + 9437184);     // 2,097,152 bf
  __bf16* q_raw = (__bf16*)(ws + 10485760);    // 2,097,152 bf
  __bf16* xb    = (__bf16*)(ws + 11534336);    // 8,388,608 bf
  __bf16* Wcat  = (__bf16*)(ws + 15728640);    // 458,752 bf
  __bf16* Gt    = xb;                          // overlay: xb dead after proj
  __bf16* St    = (__bf16*)(ws + 15958016);    // 8,388,608 bf
  float*  cpend = ws + 20152320;               // 16,384 fl

  conv_all<<<4320, 256, 0, stream>>>(x, Wv, Wk, Wq, Wa, xb, Wcat);
  proj_mfma<<<896, 256, 0, stream>>>(xb, Wcat, bv, bk, bq, ba,
                                     vt, k_raw, q_raw, a_buf);
  scan_cp<<<256, 512, 0, stream>>>(a_buf, k_raw, q_raw, kbs, qb, kt, cpend);
  gmm<<<512, 256, 0, stream>>>(vt, kt, cpend, Gt);
  scan_state<<<512, 256, 0, stream>>>(Gt, cpend, St);
  ymm<<<512, 256, 0, stream>>>(qb, kbs, vt, St, out);
}